// Round 1
// baseline (328.253 us; speedup 1.0000x reference)
//
#include <hip/hip_runtime.h>
#include <math.h>

#define NSTEPS 6
#define DT_ 0.2f
#define TXN 64           // threads in x; each owns a float4 (4 cols) -> 256 wide
#define TYN 8            // threads in y
#define MR  6            // rows per thread
#define HE  (TYN*MR)     // 48 extended rows per strip
#define INTERIOR (HE-10) // 38 valid interior rows per strip
#define NSTRIP 7         // ceil(256/38)
#define HH 256
#define WW 256

__device__ __forceinline__ void conv_row(const float4 q, float lw, float rx,
                                         float t0, float t1, float t2, float4& acc){
  // output cols c..c+3 get taps t0*in[c-1+k] + t1*in[c+k] + t2*in[c+1+k]
  acc.x = fmaf(t0, lw , fmaf(t1, q.x, fmaf(t2, q.y, acc.x)));
  acc.y = fmaf(t0, q.x, fmaf(t1, q.y, fmaf(t2, q.z, acc.y)));
  acc.z = fmaf(t0, q.y, fmaf(t1, q.z, fmaf(t2, q.w, acc.z)));
  acc.w = fmaf(t0, q.z, fmaf(t1, q.w, fmaf(t2, rx , acc.w)));
}

__global__ __launch_bounds__(TXN*TYN) void vib6_fused(
    const float* __restrict__ force, const float* __restrict__ cw,
    const float* __restrict__ omega, const float* __restrict__ zeta,
    float* __restrict__ out)
{
  const int tx = threadIdx.x;       // 0..63 == lane id (one wave per ty row)
  const int ty = threadIdx.y;       // 0..7
  const int strip = blockIdx.x;     // 0..6
  const int plane = blockIdx.y;     // b*64 + c, 0..511
  const int ch = plane & 63;

  // per-channel uniform constants
  const float om = omega[ch], ze = zeta[ch];
  const float w   = log1pf(expf(om));          // softplus
  const float z   = 1.f/(1.f + expf(-ze));     // sigmoid
  const float w2  = w*w;
  const float aco = 1.f - 2.f*z*w*DT_;         // v' = aco*v + bco*x + DT*(f+inter)
  const float bco = -w2*DT_;
  const float w2h = 0.5f*w2;
  float wdt[9];
  #pragma unroll
  for (int k=0;k<9;++k) wdt[k] = DT_*cw[ch*9+k];   // fold DT into conv taps

  // double-buffered vertical-halo exchange (only top/bottom row of each slab)
  __shared__ float4 topb[2][TYN][TXN];
  __shared__ float4 botb[2][TYN][TXN];

  const int c0 = tx<<2;
  const size_t pbase = (size_t)plane*(HH*WW);

  float4 x[MR], v[MR], F[MR];
  float msk[MR];

  // ---- load force, pre-scale by DT, and do step 1 analytically ----
  #pragma unroll
  for (int i=0;i<MR;++i){
    const int R = ty*MR + i;
    const int g = strip*INTERIOR - 5 + R;   // global row of this ext row
    const bool ok = (g>=0) && (g<HH);
    msk[i] = ok ? 1.f : 0.f;
    float4 f4 = make_float4(0.f,0.f,0.f,0.f);
    if (ok) f4 = *(const float4*)(force + pbase + (size_t)g*WW + c0);
    F[i].x = DT_*f4.x; F[i].y = DT_*f4.y; F[i].z = DT_*f4.z; F[i].w = DT_*f4.w;
    // step 1: conv(x0)=0 -> v1 = DT*f, x1 = DT*v1 (OOB rows: f=0 -> stays 0)
    v[i] = F[i];
    x[i].x = DT_*F[i].x; x[i].y = DT_*F[i].y; x[i].z = DT_*F[i].z; x[i].w = DT_*F[i].w;
  }

  const int addrL = ((tx+63)&63) << 2;
  const int addrR = ((tx+ 1)&63) << 2;
  const bool ledge = (tx==0);        // true image left edge  -> zero pad
  const bool redge = (tx==TXN-1);    // true image right edge -> zero pad

  // ---- steps 2..6 ----
  #pragma unroll
  for (int s=1; s<NSTEPS; ++s){
    const int p = s & 1;
    topb[p][ty][tx] = x[0];
    botb[p][ty][tx] = x[MR-1];
    __syncthreads();
    const float4 zero4 = make_float4(0.f,0.f,0.f,0.f);
    float4 xm1 = (ty>0)      ? botb[p][ty-1][tx] : zero4;  // ext row R0-1
    float4 xp1 = (ty<TYN-1)  ? topb[p][ty+1][tx] : zero4;  // ext row R0+MR
    // (no 2nd barrier: buffers alternate, next write to this buffer is 2 syncs away)

    // rolling accumulators: aP=row r-1, aC=row r, aN=row r+1 while scanning input row r
    float4 aP = make_float4(0,0,0,0), aC = make_float4(0,0,0,0), aN = F[0];

    #pragma unroll
    for (int jj=0; jj<=MR+1; ++jj){
      const int r = jj-1;                              // input ext-local row -1..MR
      const float4 q = (jj==0) ? xm1 : ((jj==MR+1) ? xp1 : x[jj-1]);
      float lw = __int_as_float(__builtin_amdgcn_ds_bpermute(addrL, __float_as_int(q.w)));
      lw = ledge ? 0.f : lw;
      float rx = __int_as_float(__builtin_amdgcn_ds_bpermute(addrR, __float_as_int(q.x)));
      rx = redge ? 0.f : rx;

      if (r-1 >= 0)            conv_row(q, lw, rx, wdt[6], wdt[7], wdt[8], aP); // di=2
      if (r   >= 0 && r < MR)  conv_row(q, lw, rx, wdt[3], wdt[4], wdt[5], aC); // di=1
      if (r+1 < MR)            conv_row(q, lw, rx, wdt[0], wdt[1], wdt[2], aN); // di=0

      if (r-1 >= 0){           // row r-1 is complete: finalize it
        const int i = r-1;
        v[i].x = fmaf(aco, v[i].x, fmaf(bco, x[i].x, aP.x));
        v[i].y = fmaf(aco, v[i].y, fmaf(bco, x[i].y, aP.y));
        v[i].z = fmaf(aco, v[i].z, fmaf(bco, x[i].z, aP.z));
        v[i].w = fmaf(aco, v[i].w, fmaf(bco, x[i].w, aP.w));
        x[i].x = fmaf(DT_, v[i].x, x[i].x) * msk[i];
        x[i].y = fmaf(DT_, v[i].y, x[i].y) * msk[i];
        x[i].z = fmaf(DT_, v[i].z, x[i].z) * msk[i];
        x[i].w = fmaf(DT_, v[i].w, x[i].w) * msk[i];
      }
      aP = aC; aC = aN;
      aN = (jj+1 < MR) ? F[jj+1] : make_float4(0,0,0,0);
    }
  }

  // ---- epilogue: out = 0.5 v^2 + 0.5 w^2 x^2 on interior rows ----
  #pragma unroll
  for (int i=0;i<MR;++i){
    const int R = ty*MR + i;
    if (R >= 5 && R < HE-5){
      const int g = strip*INTERIOR + (R-5);
      if (g < HH){
        float4 o;
        o.x = fmaf(0.5f*v[i].x, v[i].x, w2h*x[i].x*x[i].x);
        o.y = fmaf(0.5f*v[i].y, v[i].y, w2h*x[i].y*x[i].y);
        o.z = fmaf(0.5f*v[i].z, v[i].z, w2h*x[i].z*x[i].z);
        o.w = fmaf(0.5f*v[i].w, v[i].w, w2h*x[i].w*x[i].w);
        *(float4*)(out + pbase + (size_t)g*WW + c0) = o;
      }
    }
  }
}

extern "C" void kernel_launch(void* const* d_in, const int* in_sizes, int n_in,
                              void* d_out, int out_size, void* d_ws, size_t ws_size,
                              hipStream_t stream) {
  const float* force = (const float*)d_in[0];   // [8,64,256,256]
  const float* cw    = (const float*)d_in[1];   // [64,1,3,3]
  const float* om    = (const float*)d_in[2];   // [64]
  const float* ze    = (const float*)d_in[3];   // [64]
  float* out = (float*)d_out;                   // [8,64,256,256]
  dim3 grid(NSTRIP, 8*64);
  dim3 block(TXN, TYN);
  hipLaunchKernelGGL(vib6_fused, grid, block, 0, stream, force, cw, om, ze, out);
}

// Round 2
// 322.550 us; speedup vs baseline: 1.0177x; 1.0177x over previous
//
#include <hip/hip_runtime.h>
#include <math.h>

#define NSTEPS 6
#define DT_ 0.2f
#define TXN 64           // threads in x; each owns a float4 (4 cols) -> 256 wide
#define TYN 8            // threads in y
#define MR  6            // rows per thread
#define HE  (TYN*MR)     // 48 extended rows per strip
#define INTERIOR (HE-10) // 38 valid interior rows per strip
#define NSTRIP 7         // ceil(256/38)
#define HH 256
#define WW 256

// DPP controls (GFX9 lineage): wave_shr:1 = 0x138 (lane i <- lane i-1),
// wave_shl:1 = 0x130 (lane i <- lane i+1). bound_ctrl=1 -> OOB lanes read 0,
// which IS the conv zero-padding at image left/right edges (wave spans full row).
__device__ __forceinline__ float shl_left(float x){   // returns left-neighbor value
  return __int_as_float(__builtin_amdgcn_update_dpp(
      0, __float_as_int(x), 0x138, 0xF, 0xF, true));
}
__device__ __forceinline__ float shr_right(float x){  // returns right-neighbor value
  return __int_as_float(__builtin_amdgcn_update_dpp(
      0, __float_as_int(x), 0x130, 0xF, 0xF, true));
}

__device__ __forceinline__ void conv_row(const float4 q, float lw, float rx,
                                         float t0, float t1, float t2, float4& acc){
  // output cols c..c+3 get taps t0*in[c-1+k] + t1*in[c+k] + t2*in[c+1+k]
  acc.x = fmaf(t0, lw , fmaf(t1, q.x, fmaf(t2, q.y, acc.x)));
  acc.y = fmaf(t0, q.x, fmaf(t1, q.y, fmaf(t2, q.z, acc.y)));
  acc.z = fmaf(t0, q.y, fmaf(t1, q.z, fmaf(t2, q.w, acc.z)));
  acc.w = fmaf(t0, q.z, fmaf(t1, q.w, fmaf(t2, rx , acc.w)));
}

__global__ __launch_bounds__(TXN*TYN) void vib6_fused(
    const float* __restrict__ force, const float* __restrict__ cw,
    const float* __restrict__ omega, const float* __restrict__ zeta,
    float* __restrict__ out)
{
  const int tx = threadIdx.x;       // 0..63 == lane id (one wave per ty row)
  const int ty = threadIdx.y;       // 0..7
  const int strip = blockIdx.x;     // 0..6
  const int plane = blockIdx.y;     // b*64 + c, 0..511
  const int ch = plane & 63;

  // per-channel uniform constants
  const float om = omega[ch], ze = zeta[ch];
  const float w   = log1pf(expf(om));          // softplus
  const float z   = 1.f/(1.f + expf(-ze));     // sigmoid
  const float w2  = w*w;
  const float aco = 1.f - 2.f*z*w*DT_;         // v' = aco*v + bco*x + DT*(f+inter)
  const float bco = -w2*DT_;
  const float w2h = 0.5f*w2;
  float wdt[9];
  #pragma unroll
  for (int k=0;k<9;++k) wdt[k] = DT_*cw[ch*9+k];   // fold DT into conv taps

  // double-buffered vertical-halo exchange (only top/bottom row of each slab)
  __shared__ float4 topb[2][TYN][TXN];
  __shared__ float4 botb[2][TYN][TXN];

  const int c0 = tx<<2;
  const size_t pbase = (size_t)plane*(HH*WW);

  float4 x[MR], v[MR], F[MR];
  float msk[MR];

  // ---- load force, pre-scale by DT, and do step 1 analytically ----
  #pragma unroll
  for (int i=0;i<MR;++i){
    const int R = ty*MR + i;
    const int g = strip*INTERIOR - 5 + R;   // global row of this ext row
    const bool ok = (g>=0) && (g<HH);
    msk[i] = ok ? 1.f : 0.f;
    float4 f4 = make_float4(0.f,0.f,0.f,0.f);
    if (ok) f4 = *(const float4*)(force + pbase + (size_t)g*WW + c0);
    F[i].x = DT_*f4.x; F[i].y = DT_*f4.y; F[i].z = DT_*f4.z; F[i].w = DT_*f4.w;
    // step 1: conv(x0)=0 -> v1 = DT*f, x1 = DT*v1 (OOB rows: f=0 -> stays 0)
    v[i] = F[i];
    x[i].x = DT_*F[i].x; x[i].y = DT_*F[i].y; x[i].z = DT_*F[i].z; x[i].w = DT_*F[i].w;
  }

  // ---- steps 2..6 ----
  #pragma unroll
  for (int s=1; s<NSTEPS; ++s){
    const int p = s & 1;
    topb[p][ty][tx] = x[0];
    botb[p][ty][tx] = x[MR-1];
    __syncthreads();
    const float4 zero4 = make_float4(0.f,0.f,0.f,0.f);
    float4 xm1 = (ty>0)      ? botb[p][ty-1][tx] : zero4;  // ext row R0-1
    float4 xp1 = (ty<TYN-1)  ? topb[p][ty+1][tx] : zero4;  // ext row R0+MR
    // (no 2nd barrier: buffers alternate, next write to this buffer is 2 syncs away)

    // rolling accumulators: aP=row r-1, aC=row r, aN=row r+1 while scanning input row r
    float4 aP = make_float4(0,0,0,0), aC = make_float4(0,0,0,0), aN = F[0];

    #pragma unroll
    for (int jj=0; jj<=MR+1; ++jj){
      const int r = jj-1;                              // input ext-local row -1..MR
      const float4 q = (jj==0) ? xm1 : ((jj==MR+1) ? xp1 : x[jj-1]);
      const float lw = shl_left(q.w);    // left neighbor's col (zero at image edge)
      const float rx = shr_right(q.x);   // right neighbor's col (zero at image edge)

      if (r-1 >= 0)            conv_row(q, lw, rx, wdt[6], wdt[7], wdt[8], aP); // di=2
      if (r   >= 0 && r < MR)  conv_row(q, lw, rx, wdt[3], wdt[4], wdt[5], aC); // di=1
      if (r+1 < MR)            conv_row(q, lw, rx, wdt[0], wdt[1], wdt[2], aN); // di=0

      if (r-1 >= 0){           // row r-1 is complete: finalize it
        const int i = r-1;
        v[i].x = fmaf(aco, v[i].x, fmaf(bco, x[i].x, aP.x));
        v[i].y = fmaf(aco, v[i].y, fmaf(bco, x[i].y, aP.y));
        v[i].z = fmaf(aco, v[i].z, fmaf(bco, x[i].z, aP.z));
        v[i].w = fmaf(aco, v[i].w, fmaf(bco, x[i].w, aP.w));
        x[i].x = fmaf(DT_, v[i].x, x[i].x) * msk[i];
        x[i].y = fmaf(DT_, v[i].y, x[i].y) * msk[i];
        x[i].z = fmaf(DT_, v[i].z, x[i].z) * msk[i];
        x[i].w = fmaf(DT_, v[i].w, x[i].w) * msk[i];
      }
      aP = aC; aC = aN;
      aN = (jj+1 < MR) ? F[jj+1] : make_float4(0,0,0,0);
    }
  }

  // ---- epilogue: out = 0.5 v^2 + 0.5 w^2 x^2 on interior rows ----
  #pragma unroll
  for (int i=0;i<MR;++i){
    const int R = ty*MR + i;
    if (R >= 5 && R < HE-5){
      const int g = strip*INTERIOR + (R-5);
      if (g < HH){
        float4 o;
        o.x = fmaf(0.5f*v[i].x, v[i].x, w2h*x[i].x*x[i].x);
        o.y = fmaf(0.5f*v[i].y, v[i].y, w2h*x[i].y*x[i].y);
        o.z = fmaf(0.5f*v[i].z, v[i].z, w2h*x[i].z*x[i].z);
        o.w = fmaf(0.5f*v[i].w, v[i].w, w2h*x[i].w*x[i].w);
        *(float4*)(out + pbase + (size_t)g*WW + c0) = o;
      }
    }
  }
}

extern "C" void kernel_launch(void* const* d_in, const int* in_sizes, int n_in,
                              void* d_out, int out_size, void* d_ws, size_t ws_size,
                              hipStream_t stream) {
  const float* force = (const float*)d_in[0];   // [8,64,256,256]
  const float* cw    = (const float*)d_in[1];   // [64,1,3,3]
  const float* om    = (const float*)d_in[2];   // [64]
  const float* ze    = (const float*)d_in[3];   // [64]
  float* out = (float*)d_out;                   // [8,64,256,256]
  dim3 grid(NSTRIP, 8*64);
  dim3 block(TXN, TYN);
  hipLaunchKernelGGL(vib6_fused, grid, block, 0, stream, force, cw, om, ze, out);
}